// Round 7
// baseline (222.172 us; speedup 1.0000x reference)
//
#include <hip/hip_runtime.h>
#include <stdint.h>

typedef unsigned short ushort_t;
typedef __attribute__((ext_vector_type(8))) short short8;
typedef __attribute__((ext_vector_type(4))) short s16x4;
typedef __attribute__((ext_vector_type(4))) float f32x4;
typedef __attribute__((ext_vector_type(2))) uint32_t u32x2;

#define BATCH 4
#define SEQ 2048
#define DMODEL 768
#define NH 12
#define HD 64
#define QKV3 2304
#define NHEADS 48
// 0.125 (1/sqrt(64)) * log2(e): Q pre-scaled so softmax uses exp2
#define SCALE_Q 0.18033688011112042f

__device__ __forceinline__ ushort_t f2bf(float f) {
    union { float f; uint32_t u; } v; v.f = f;
    uint32_t u = v.u;
    u += 0x7FFF + ((u >> 16) & 1);   // RNE
    return (ushort_t)(u >> 16);
}

// pack two fp32 -> bf16x2 dword, RNE (HW packed convert when available)
__device__ __forceinline__ uint32_t pack_bf16(float a, float b) {
#if __has_builtin(__builtin_amdgcn_cvt_pk_bf16_f32)
    typedef __attribute__((ext_vector_type(2))) __bf16 bf16x2;
    bf16x2 r = __builtin_amdgcn_cvt_pk_bf16_f32(a, b);
    return __builtin_bit_cast(uint32_t, r);
#else
    return ((uint32_t)f2bf(b) << 16) | (uint32_t)f2bf(a);
#endif
}

// async global->LDS, 16B per lane; LDS dst = wave-uniform base + lane*16
typedef __attribute__((address_space(1))) uint32_t as1_u32;
typedef __attribute__((address_space(3))) uint32_t as3_u32;
__device__ __forceinline__ void async16(void* lds, const void* gsrc) {
    __builtin_amdgcn_global_load_lds((as1_u32*)gsrc, (as3_u32*)lds, 16, 0, 0);
}

// full drain: vmcnt(0) expcnt(7=nowait) lgkmcnt(0)
__device__ __forceinline__ void wait_vm_lgkm0() {
    __builtin_amdgcn_s_waitcnt(0x0070);
}

// K=16 bf16 MFMA (P^T stays in registers as the B operand)
__device__ __forceinline__ f32x4 mfma16x16x16bf16(s16x4 a, s16x4 b, f32x4 c) {
#if __has_builtin(__builtin_amdgcn_mfma_f32_16x16x16bf16_1k)
    return __builtin_amdgcn_mfma_f32_16x16x16bf16_1k(a, b, c, 0, 0, 0);
#else
    f32x4 d;
    asm volatile("v_mfma_f32_16x16x16_bf16 %0, %1, %2, %3"
                 : "=&v"(d) : "v"(a), "v"(b), "0"(c));
    return d;
#endif
}

// ---------------------------------------------------------------------------
// prep kernels
// ---------------------------------------------------------------------------
__global__ __launch_bounds__(256) void cvt_bf16(
    const float* __restrict__ in, ushort_t* __restrict__ out) {
    int i = blockIdx.x * 256 + threadIdx.x;
    float4 v = *(const float4*)(in + (size_t)i * 4);
    ushort4 o; o.x = f2bf(v.x); o.y = f2bf(v.y); o.z = f2bf(v.z); o.w = f2bf(v.w);
    *(ushort4*)(out + (size_t)i * 4) = o;
}

__global__ __launch_bounds__(256) void transpose_f32_bf16(
    const float* __restrict__ in, ushort_t* __restrict__ out, int R, int C) {
    __shared__ ushort_t t[64][72];
    const int tid = threadIdx.x;
    const int r0 = blockIdx.y * 64, c0 = blockIdx.x * 64;
#pragma unroll
    for (int i = 0; i < 4; i++) {
        int idx = tid + i * 256;
        int row = idx >> 4, c4 = (idx & 15) * 4;
        float4 v = *(const float4*)(in + (size_t)(r0 + row) * C + c0 + c4);
        ushort4 o; o.x = f2bf(v.x); o.y = f2bf(v.y); o.z = f2bf(v.z); o.w = f2bf(v.w);
        *(ushort4*)&t[row][c4] = o;
    }
    __syncthreads();
#pragma unroll
    for (int i = 0; i < 2; i++) {
        int idx = tid + i * 256;
        int oc = idx >> 3, g8 = (idx & 7) * 8;
        ushort_t tmp[8];
#pragma unroll
        for (int e = 0; e < 8; e++) tmp[e] = t[g8 + e][oc];
        *(short8*)(out + (size_t)(c0 + oc) * R + r0 + g8) = *(const short8*)tmp;
    }
}

// ---------------------------------------------------------------------------
// GEMM1: qkv = xb @ wqT^T. Q/K scattered to [which][b][h][n][d] (Q scaled);
// V written DIRECTLY transposed to vT[b*12+h][d][n] (8B token-packed stores).
// ---------------------------------------------------------------------------
__global__ __launch_bounds__(256, 2) void gemm_qkv(
    const ushort_t* __restrict__ A, const ushort_t* __restrict__ B,
    ushort_t* __restrict__ qkv, ushort_t* __restrict__ vT) {
    __shared__ ushort_t As[128 * 64];
    __shared__ ushort_t Bs[128 * 64];

    const int tid = threadIdx.x;
    const int m0 = blockIdx.y * 128, n0 = blockIdx.x * 128;
    const int lane = tid & 63, w = tid >> 6;
    const int wm = w >> 1, wn = w & 1;
    const int l16 = lane & 15, quad = lane >> 4;

    f32x4 acc[4][4];
#pragma unroll
    for (int i = 0; i < 4; i++)
#pragma unroll
        for (int j = 0; j < 4; j++) acc[i][j] = (f32x4){0.f, 0.f, 0.f, 0.f};

    int srow[4], scol[4];
#pragma unroll
    for (int j = 0; j < 4; j++) {
        int s = j * 256 + tid;
        srow[j] = s >> 3;
        scol[j] = ((s & 7) ^ (srow[j] & 7)) * 8;
    }
    const int swz0 = (quad ^ (l16 & 7)) * 8;
    const int swz1 = ((4 + quad) ^ (l16 & 7)) * 8;

    for (int kt = 0; kt < DMODEL; kt += 64) {
#pragma unroll
        for (int j = 0; j < 4; j++) {
            async16(&As[(j * 256 + w * 64) * 8],
                    A + (size_t)(m0 + srow[j]) * DMODEL + kt + scol[j]);
            async16(&Bs[(j * 256 + w * 64) * 8],
                    B + (size_t)(n0 + srow[j]) * DMODEL + kt + scol[j]);
        }
        wait_vm_lgkm0();
        __syncthreads();

        short8 a[4][2], b[4][2];
#pragma unroll
        for (int mi = 0; mi < 4; mi++) {
            int r = (wm * 64 + mi * 16 + l16) * 64;
            a[mi][0] = *(const short8*)&As[r + swz0];
            a[mi][1] = *(const short8*)&As[r + swz1];
        }
#pragma unroll
        for (int ni = 0; ni < 4; ni++) {
            int r = (wn * 64 + ni * 16 + l16) * 64;
            b[ni][0] = *(const short8*)&Bs[r + swz0];
            b[ni][1] = *(const short8*)&Bs[r + swz1];
        }
#pragma unroll
        for (int kk = 0; kk < 2; kk++)
#pragma unroll
            for (int mi = 0; mi < 4; mi++)
#pragma unroll
                for (int ni = 0; ni < 4; ni++)
                    acc[mi][ni] = __builtin_amdgcn_mfma_f32_16x16x32_bf16(
                        a[mi][kk], b[ni][kk], acc[mi][ni], 0, 0, 0);
        __syncthreads();
    }

#pragma unroll
    for (int ni = 0; ni < 4; ni++) {
        int nbase = n0 + wn * 64 + ni * 16;
        int which = nbase / DMODEL;           // block-uniform per ni
        int rem = nbase - which * DMODEL;
        int h = rem >> 6;
        int d = (rem & 63) + l16;
        if (which == 2) {
            // V^T direct: [b*12+h][d][token], 4 consecutive tokens per lane
#pragma unroll
            for (int mi = 0; mi < 4; mi++) {
                int mg = m0 + wm * 64 + mi * 16 + quad * 4;
                int b_ = mg >> 11, ns = mg & 2047;
                u32x2 pk = {pack_bf16(acc[mi][ni][0], acc[mi][ni][1]),
                            pack_bf16(acc[mi][ni][2], acc[mi][ni][3])};
                *(u32x2*)(vT + ((size_t)(b_ * NH + h) * HD + d) * SEQ + ns) = pk;
            }
        } else {
            float scale = (which == 0) ? SCALE_Q : 1.0f;
#pragma unroll
            for (int mi = 0; mi < 4; mi++) {
#pragma unroll
                for (int r = 0; r < 4; r++) {
                    int mg = m0 + wm * 64 + mi * 16 + quad * 4 + r;
                    int b_ = mg >> 11, ns = mg & 2047;
                    size_t dst = (((size_t)(which * BATCH + b_) * NH + h) * SEQ + ns) * HD + d;
                    qkv[dst] = f2bf(acc[mi][ni][r] * scale);
                }
            }
        }
    }
}

// ---------------------------------------------------------------------------
// Flash attention: S^T form, fixed-zero-max softmax, MONOLITHIC tile body
// (R5 structure — max ILP per stage), 3-buffer distance-2 prefetch pipeline
// with raw s_barrier + manual s_waitcnt (vmcnt(4): keep next prefetch in
// flight across the barrier; lgkmcnt(0): seal our LDS reads pre-barrier).
// XCD-swizzled block mapping for K/V L2 locality.
// ---------------------------------------------------------------------------
__global__ __launch_bounds__(256, 3) void attn(
    const ushort_t* __restrict__ qkv, const ushort_t* __restrict__ vT,
    ushort_t* __restrict__ ao) {
    __shared__ ushort_t smem[3 * 8192];   // 3 bufs x (K 4096 | V 4096) elems

    const int tid = threadIdx.x;
    // XCD swizzle: all 16 Q-blocks of a head land on one XCD (bid%8 == XCD)
    const int bid = blockIdx.x;
    const int i = bid >> 3;
    const int bh = (bid & 7) + 8 * (i % 6);
    const int qt = i / 6;
    const int lane = tid & 63, w = tid >> 6;
    const int l16 = lane & 15, quad = lane >> 4;
    const int qh7 = l16 & 7, qhi = quad >> 1, qlo4 = (quad & 1) * 4;

    const ushort_t* qh = qkv + (size_t)bh * (SEQ * HD);
    const ushort_t* kh = qkv + (size_t)(NHEADS + bh) * (SEQ * HD);
    const ushort_t* vh = vT + (size_t)bh * (HD * SEQ);

    short8 aq[2][2];
#pragma unroll
    for (int mi = 0; mi < 2; mi++)
#pragma unroll
        for (int kk = 0; kk < 2; kk++) {
            int row = qt * 128 + w * 32 + mi * 16 + l16;
            aq[mi][kk] = *(const short8*)(qh + (size_t)row * HD + kk * 32 + quad * 8);
        }

    f32x4 lv[2];
    f32x4 O[4][2];
#pragma unroll
    for (int mi = 0; mi < 2; mi++) lv[mi] = (f32x4){0.f, 0.f, 0.f, 0.f};
#pragma unroll
    for (int nd = 0; nd < 4; nd++)
#pragma unroll
        for (int mi = 0; mi < 2; mi++) O[nd][mi] = (f32x4){0.f, 0.f, 0.f, 0.f};

    int srow[2], scol[2];
#pragma unroll
    for (int j = 0; j < 2; j++) {
        int s = j * 256 + tid;
        srow[j] = s >> 3;
        scol[j] = ((s & 7) ^ (srow[j] & 7)) * 8;
    }
    const int swz0 = (quad ^ qh7) * 8;
    const int swz1 = ((4 + quad) ^ qh7) * 8;

    // prologue: prefetch tiles 0 and 1 into bufs 0 and 1 (4 vm insts each)
#pragma unroll
    for (int pt = 0; pt < 2; pt++) {
        int nb = pt * 8192, j1 = pt * 64;
#pragma unroll
        for (int j = 0; j < 2; j++) {
            async16(&smem[nb + (j * 256 + w * 64) * 8],
                    kh + (size_t)(j1 + srow[j]) * HD + scol[j]);
            async16(&smem[nb + 4096 + (j * 256 + w * 64) * 8],
                    vh + (size_t)srow[j] * SEQ + j1 + scol[j]);
        }
    }

    const int NT = SEQ / 64;
    int buf = 0;          // buffer holding tile t
    int pf = 2;           // buffer to prefetch into (tile t+2)
    for (int t = 0; t < NT; t++) {
        // drain prefetch(t) only; prefetch(t+1) stays in flight across barrier
        if (t == NT - 1)
            __builtin_amdgcn_s_waitcnt(0x0070);   // vmcnt(0) lgkmcnt(0)
        else
            __builtin_amdgcn_s_waitcnt(0x0074);   // vmcnt(4) lgkmcnt(0)
        asm volatile("s_barrier" ::: "memory");

        if (t + 2 < NT) {
            int nb = pf * 8192, j1 = (t + 2) * 64;
#pragma unroll
            for (int j = 0; j < 2; j++) {
                async16(&smem[nb + (j * 256 + w * 64) * 8],
                        kh + (size_t)(j1 + srow[j]) * HD + scol[j]);
                async16(&smem[nb + 4096 + (j * 256 + w * 64) * 8],
                        vh + (size_t)srow[j] * SEQ + j1 + scol[j]);
            }
        }
        const ushort_t* Ks = smem + buf * 8192;
        const ushort_t* Vs = Ks + 4096;
        buf = (buf == 2) ? 0 : buf + 1;
        pf = (pf == 2) ? 0 : pf + 1;

        // ---- stage 1: all 8 QK MFMAs (independent) ----
        f32x4 S[4][2];
        short8 ak[4][2];
#pragma unroll
        for (int ni = 0; ni < 4; ni++) {
            int r = (ni * 16 + l16) * 64;
            ak[ni][0] = *(const short8*)&Ks[r + swz0];
            ak[ni][1] = *(const short8*)&Ks[r + swz1];
        }
#pragma unroll
        for (int ni = 0; ni < 4; ni++)
#pragma unroll
            for (int mi = 0; mi < 2; mi++) {
                f32x4 s = __builtin_amdgcn_mfma_f32_16x16x32_bf16(
                    ak[ni][0], aq[mi][0], (f32x4){0.f, 0.f, 0.f, 0.f}, 0, 0, 0);
                S[ni][mi] = __builtin_amdgcn_mfma_f32_16x16x32_bf16(
                    ak[ni][1], aq[mi][1], s, 0, 0, 0);
            }

        // ---- stage 2: all 32 exps (independent) + l accumulation ----
#pragma unroll
        for (int mi = 0; mi < 2; mi++)
#pragma unroll
            for (int ni = 0; ni < 4; ni++) {
                f32x4 p;
#pragma unroll
                for (int rr = 0; rr < 4; rr++)
                    p[rr] = __builtin_amdgcn_exp2f(S[ni][mi][rr]);
                S[ni][mi] = p;
                lv[mi] += p;
            }

        // ---- stage 3: pack P^T and all 32 PV MFMAs ----
#pragma unroll
        for (int kb = 0; kb < 4; kb++) {
            s16x4 bp[2];
#pragma unroll
            for (int mi = 0; mi < 2; mi++)
                bp[mi] = __builtin_bit_cast(
                    s16x4, (u32x2){pack_bf16(S[kb][mi][0], S[kb][mi][1]),
                                   pack_bf16(S[kb][mi][2], S[kb][mi][3])});
#pragma unroll
            for (int nd = 0; nd < 4; nd++) {
                int vrow = nd * 16 + l16;
                s16x4 av = *(const s16x4*)&Vs[vrow * 64 +
                                              (((kb * 2 + qhi) ^ qh7) * 8) + qlo4];
#pragma unroll
                for (int mi = 0; mi < 2; mi++)
                    O[nd][mi] = mfma16x16x16bf16(av, bp[mi], O[nd][mi]);
            }
        }
    }

    // epilogue: reduce l, transpose O^T via LDS, coalesced store
    float inv[2];
#pragma unroll
    for (int mi = 0; mi < 2; mi++) {
        float l = (lv[mi][0] + lv[mi][1]) + (lv[mi][2] + lv[mi][3]);
        l += __shfl_xor(l, 16, 64);
        l += __shfl_xor(l, 32, 64);
        inv[mi] = __builtin_amdgcn_rcpf(l);
    }
    wait_vm_lgkm0();
    asm volatile("s_barrier" ::: "memory");
    ushort_t* Lt = smem;   // [128][72]
#pragma unroll
    for (int mi = 0; mi < 2; mi++)
#pragma unroll
        for (int nd = 0; nd < 4; nd++) {
            int row = w * 32 + mi * 16 + l16;
            int col = nd * 16 + quad * 4;
            uint32_t d0 = pack_bf16(O[nd][mi][0] * inv[mi], O[nd][mi][1] * inv[mi]);
            uint32_t d1 = pack_bf16(O[nd][mi][2] * inv[mi], O[nd][mi][3] * inv[mi]);
            *(u32x2*)&Lt[row * 72 + col] = (u32x2){d0, d1};
        }
    wait_vm_lgkm0();
    asm volatile("s_barrier" ::: "memory");

    const int b_ = bh / NH, h = bh % NH;
#pragma unroll
    for (int i2 = 0; i2 < 4; i2++) {
        int idx = tid + i2 * 256;
        int row = idx >> 3, c8 = (idx & 7) * 8;
        short8 vv = *(const short8*)&Lt[row * 72 + c8];
        *(short8*)(ao + ((size_t)(b_ * SEQ + qt * 128 + row)) * DMODEL +
                   h * HD + c8) = vv;
    }
}

// ---------------------------------------------------------------------------
// GEMM2 (unchanged)
// ---------------------------------------------------------------------------
__global__ __launch_bounds__(256, 2) void gemm_out(
    const ushort_t* __restrict__ A, const ushort_t* __restrict__ B,
    const float* __restrict__ bias, float* __restrict__ out) {
    __shared__ ushort_t As[128 * 64];
    __shared__ ushort_t Bs[128 * 64];

    const int tid = threadIdx.x;
    const int m0 = blockIdx.y * 128, n0 = blockIdx.x * 128;
    const int lane = tid & 63, w = tid >> 6;
    const int wm = w >> 1, wn = w & 1;
    const int l16 = lane & 15, quad = lane >> 4;

    f32x4 acc[4][4];
#pragma unroll
    for (int i = 0; i < 4; i++)
#pragma unroll
        for (int j = 0; j < 4; j++) acc[i][j] = (f32x4){0.f, 0.f, 0.f, 0.f};

    int srow[4], scol[4];
#pragma unroll
    for (int j = 0; j < 4; j++) {
        int s = j * 256 + tid;
        srow[j] = s >> 3;
        scol[j] = ((s & 7) ^ (srow[j] & 7)) * 8;
    }
    const int swz0 = (quad ^ (l16 & 7)) * 8;
    const int swz1 = ((4 + quad) ^ (l16 & 7)) * 8;

    for (int kt = 0; kt < DMODEL; kt += 64) {
#pragma unroll
        for (int j = 0; j < 4; j++) {
            async16(&As[(j * 256 + w * 64) * 8],
                    A + (size_t)(m0 + srow[j]) * DMODEL + kt + scol[j]);
            async16(&Bs[(j * 256 + w * 64) * 8],
                    B + (size_t)(n0 + srow[j]) * DMODEL + kt + scol[j]);
        }
        wait_vm_lgkm0();
        __syncthreads();

        short8 a[4][2], b[4][2];
#pragma unroll
        for (int mi = 0; mi < 4; mi++) {
            int r = (wm * 64 + mi * 16 + l16) * 64;
            a[mi][0] = *(const short8*)&As[r + swz0];
            a[mi][1] = *(const short8*)&As[r + swz1];
        }
#pragma unroll
        for (int ni = 0; ni < 4; ni++) {
            int r = (wn * 64 + ni * 16 + l16) * 64;
            b[ni][0] = *(const short8*)&Bs[r + swz0];
            b[ni][1] = *(const short8*)&Bs[r + swz1];
        }
#pragma unroll
        for (int kk = 0; kk < 2; kk++)
#pragma unroll
            for (int mi = 0; mi < 4; mi++)
#pragma unroll
                for (int ni = 0; ni < 4; ni++)
                    acc[mi][ni] = __builtin_amdgcn_mfma_f32_16x16x32_bf16(
                        a[mi][kk], b[ni][kk], acc[mi][ni], 0, 0, 0);
        __syncthreads();
    }

#pragma unroll
    for (int ni = 0; ni < 4; ni++) {
        int ng = n0 + wn * 64 + ni * 16 + l16;
        float bv = bias[ng];
#pragma unroll
        for (int mi = 0; mi < 4; mi++) {
#pragma unroll
            for (int r = 0; r < 4; r++) {
                int mg = m0 + wm * 64 + mi * 16 + quad * 4 + r;
                out[(size_t)mg * DMODEL + ng] = acc[mi][ni][r] + bv;
            }
        }
    }
}

extern "C" void kernel_launch(void* const* d_in, const int* in_sizes, int n_in,
                              void* d_out, int out_size, void* d_ws, size_t ws_size,
                              hipStream_t stream) {
    const float* x     = (const float*)d_in[0];
    const float* w_qkv = (const float*)d_in[1];
    const float* w_out = (const float*)d_in[2];
    const float* b_out = (const float*)d_in[3];
    float* out = (float*)d_out;

    ushort_t* xb  = (ushort_t*)d_ws;                       // 8192*768
    ushort_t* wqT = xb  + (size_t)8192 * 768;              // 2304*768
    ushort_t* woT = wqT + (size_t)QKV3 * 768;              // 768*768
    ushort_t* qkv = woT + (size_t)768 * 768;               // 3*48*2048*64 (V region unused)
    ushort_t* vT  = qkv + (size_t)3 * NHEADS * SEQ * HD;   // 48*64*2048
    ushort_t* ao  = vT  + (size_t)NHEADS * HD * SEQ;       // 8192*768

    cvt_bf16<<<dim3((8192 * 768) / 4 / 256), 256, 0, stream>>>(x, xb);
    transpose_f32_bf16<<<dim3(QKV3 / 64, DMODEL / 64), 256, 0, stream>>>(
        w_qkv, wqT, DMODEL, QKV3);
    transpose_f32_bf16<<<dim3(DMODEL / 64, DMODEL / 64), 256, 0, stream>>>(
        w_out, woT, DMODEL, DMODEL);

    gemm_qkv<<<dim3(QKV3 / 128, (BATCH * SEQ) / 128), 256, 0, stream>>>(
        xb, wqT, qkv, vT);

    attn<<<dim3(NHEADS * (SEQ / 128)), 256, 0, stream>>>(qkv, vT, ao);

    gemm_out<<<dim3(DMODEL / 128, (BATCH * SEQ) / 128), 256, 0, stream>>>(
        ao, woT, b_out, out);
}